// Round 5
// baseline (746.849 us; speedup 1.0000x reference)
//
#include <hip/hip_runtime.h>
#include <hip/hip_fp16.h>
#include <math.h>

#define NN 100000
#define NE 3200000
#define INF_ 128
#define D 32
#define H 4
#define HD 8

// binning config: bucket = dst >> 8 (256 dst nodes per bucket)
#define BSH 8
#define BNODES 256
#define NBKT 391                // ceil(100000/256)
#define NBLK 128                // chunking blocks for passes A/C
#define EPB (NE / NBLK)         // 25000 edges per block
#define CAP 12288               // LDS sorted capacity

__device__ __forceinline__ float gelu_f(float x) {
    return 0.5f * x * (1.0f + erff(x * 0.70710678118654752f));
}

// h = gelu(x @ W_in + b_in); block = 256 threads = 8 nodes x 32 cols
__global__ __launch_bounds__(256) void k_in_proj(const float* __restrict__ x,
        const float* __restrict__ W, const float* __restrict__ b,
        float* __restrict__ h) {
    __shared__ float Ws[INF_ * D];     // 16 KB
    __shared__ float xs[8][INF_];      // 4 KB
    for (int i = threadIdx.x; i < INF_ * D; i += 256) Ws[i] = W[i];
    int ln = threadIdx.x >> 5;
    int col = threadIdx.x & 31;
    int node = blockIdx.x * 8 + ln;    // NN/8 = 12500 exact
    const float4* xr = (const float4*)(x + (size_t)node * INF_);
    ((float4*)xs[ln])[col] = xr[col];
    __syncthreads();
    float acc = b[col];
    #pragma unroll 16
    for (int i = 0; i < INF_; ++i) acc = fmaf(xs[ln][i], Ws[i * D + col], acc);
    h[(size_t)node * D + col] = gelu_f(acc);
}

// q,k,v = h @ {Wq,Wk,Wv} + bias; 8 nodes per block; fp16 head-split outputs:
// qh[h][node][8] (16B rows)
__global__ __launch_bounds__(256) void k_qkv(const float* __restrict__ h,
        const float* __restrict__ Wq, const float* __restrict__ bq,
        const float* __restrict__ Wk, const float* __restrict__ bk,
        const float* __restrict__ Wv, const float* __restrict__ bv,
        __half* __restrict__ qh, __half* __restrict__ kh, __half* __restrict__ vh) {
    __shared__ float Ws[3 * D * D];    // 12 KB
    __shared__ float hs[8][D];
    for (int i = threadIdx.x; i < D * D; i += 256) {
        Ws[i] = Wq[i];
        Ws[D * D + i] = Wk[i];
        Ws[2 * D * D + i] = Wv[i];
    }
    int ln = threadIdx.x >> 5, col = threadIdx.x & 31;
    int node = blockIdx.x * 8 + ln;
    hs[ln][col] = h[(size_t)node * D + col];
    __syncthreads();
    float aq = bq[col], ak = bk[col], av = bv[col];
    #pragma unroll
    for (int i = 0; i < D; ++i) {
        float hv = hs[ln][i];
        aq = fmaf(hv, Ws[i * D + col], aq);
        ak = fmaf(hv, Ws[D * D + i * D + col], ak);
        av = fmaf(hv, Ws[2 * D * D + i * D + col], av);
    }
    int hh = col >> 3, d = col & 7;
    size_t o = ((size_t)hh * NN + node) * HD + d;
    qh[o] = __float2half(aq); kh[o] = __float2half(ak); vh[o] = __float2half(av);
}

// ---- binned CSR build ----
__global__ __launch_bounds__(256) void k_binA(const int* __restrict__ dst,
        int* __restrict__ bhist) {
    __shared__ int hist[NBKT];
    for (int i = threadIdx.x; i < NBKT; i += 256) hist[i] = 0;
    __syncthreads();
    int base = blockIdx.x * EPB;
    for (int i = threadIdx.x; i < EPB; i += 256)
        atomicAdd(&hist[dst[base + i] >> BSH], 1);
    __syncthreads();
    for (int i = threadIdx.x; i < NBKT; i += 256)
        bhist[i * NBLK + blockIdx.x] = hist[i];
}

__global__ __launch_bounds__(NBLK) void k_binB1(int* __restrict__ bhist,
        int* __restrict__ btot) {
    __shared__ int s[NBLK];
    int b = blockIdx.x;
    int v = bhist[b * NBLK + threadIdx.x];
    s[threadIdx.x] = v;
    __syncthreads();
    for (int off = 1; off < NBLK; off <<= 1) {
        int t = (threadIdx.x >= off) ? s[threadIdx.x - off] : 0;
        __syncthreads();
        s[threadIdx.x] += t;
        __syncthreads();
    }
    bhist[b * NBLK + threadIdx.x] = s[threadIdx.x] - v;
    if (threadIdx.x == NBLK - 1) btot[b] = s[NBLK - 1];
}

__global__ __launch_bounds__(512) void k_binB2(const int* __restrict__ btot,
        int* __restrict__ bbase) {
    __shared__ int s[512];
    int v = (threadIdx.x < NBKT) ? btot[threadIdx.x] : 0;
    s[threadIdx.x] = v;
    __syncthreads();
    for (int off = 1; off < 512; off <<= 1) {
        int t = (threadIdx.x >= off) ? s[threadIdx.x - off] : 0;
        __syncthreads();
        s[threadIdx.x] += t;
        __syncthreads();
    }
    if (threadIdx.x < NBKT) bbase[threadIdx.x] = s[threadIdx.x] - v;
    if (threadIdx.x == NBKT - 1) bbase[NBKT] = s[threadIdx.x];
}

__global__ __launch_bounds__(256) void k_binC(const int* __restrict__ src,
        const int* __restrict__ dst, const int* __restrict__ bhist,
        const int* __restrict__ bbase, unsigned int* __restrict__ tmp) {
    __shared__ int offs[NBKT];
    for (int i = threadIdx.x; i < NBKT; i += 256)
        offs[i] = bhist[i * NBLK + blockIdx.x] + bbase[i];
    __syncthreads();
    int base = blockIdx.x * EPB;
    for (int i = threadIdx.x; i < EPB; i += 256) {
        int d = dst[base + i];
        unsigned int sn = (unsigned int)src[base + i];
        int pos = atomicAdd(&offs[d >> BSH], 1);
        tmp[pos] = sn | ((unsigned int)(d & (BNODES - 1)) << 17);
    }
}

__global__ __launch_bounds__(256) void k_binD(const unsigned int* __restrict__ tmp,
        const int* __restrict__ bbase, int* __restrict__ csr,
        int* __restrict__ rs, int* __restrict__ deg) {
    __shared__ int lcnt[BNODES];
    __shared__ int lscan[BNODES];
    __shared__ int sorted[CAP];
    int b = blockIdx.x;
    int s0 = bbase[b], s1 = bbase[b + 1];
    int len = s1 - s0;
    lcnt[threadIdx.x] = 0;
    __syncthreads();
    for (int i = s0 + threadIdx.x; i < s1; i += 256)
        atomicAdd(&lcnt[tmp[i] >> 17], 1);
    __syncthreads();
    int v = lcnt[threadIdx.x];
    lscan[threadIdx.x] = v;
    __syncthreads();
    for (int off = 1; off < BNODES; off <<= 1) {
        int t = (threadIdx.x >= off) ? lscan[threadIdx.x - off] : 0;
        __syncthreads();
        lscan[threadIdx.x] += t;
        __syncthreads();
    }
    int excl = lscan[threadIdx.x] - v;
    int node = (b << BSH) + threadIdx.x;
    if (node < NN) {
        rs[node] = s0 + excl;
        deg[node] = v;
    }
    lcnt[threadIdx.x] = excl;
    __syncthreads();
    if (len <= CAP) {
        for (int i = s0 + threadIdx.x; i < s1; i += 256) {
            unsigned int p = tmp[i];
            int pos = atomicAdd(&lcnt[p >> 17], 1);
            sorted[pos] = (int)(p & 0x1FFFFu);
        }
        __syncthreads();
        for (int j = threadIdx.x; j < len; j += 256)
            csr[s0 + j] = sorted[j];
    } else {
        for (int i = s0 + threadIdx.x; i < s1; i += 256) {
            unsigned int p = tmp[i];
            int pos = atomicAdd(&lcnt[p >> 17], 1);
            csr[s0 + pos] = (int)(p & 0x1FFFFu);
        }
    }
}

// per-(node,head) attention: one wave = one node for one head, 64 edge slots.
// head pinned to XCD pair via blockIdx%8 (L2 working set q_h+v_h = 3.2MB < 4MB).
__global__ __launch_bounds__(256) void k_attn(const __half* __restrict__ qh,
        const __half* __restrict__ kh, const __half* __restrict__ vh,
        const int* __restrict__ rs, const int* __restrict__ deg,
        const int* __restrict__ csr, float* __restrict__ attn) {
    int bid = blockIdx.x;
    int head = (bid & 7) >> 1;                 // XCD pair {2h, 2h+1}
    int grp = (bid >> 3) * 2 + (bid & 1);      // [0, 25000) per head
    int lane = threadIdx.x & 63;
    int node = grp * 4 + (threadIdx.x >> 6);   // [0, 100000) exact
    const __half* qb = qh + (size_t)head * NN * HD;
    const __half* vb = vh + (size_t)head * NN * HD;
    union HF { float4 f4; __half2 h2[4]; };
    HF ku;
    ku.f4 = *(const float4*)(kh + ((size_t)head * NN + node) * HD);
    float kf[HD];
    #pragma unroll
    for (int i = 0; i < 4; ++i) {
        float2 t = __half22float2(ku.h2[i]);
        kf[2 * i] = t.x; kf[2 * i + 1] = t.y;
    }
    int start = rs[node], g = deg[node];
    float m = -INFINITY, l = 0.f;
    float acc[HD];
    #pragma unroll
    for (int i = 0; i < HD; ++i) acc[i] = 0.f;
    for (int base = 0; base < g; base += 64) {
        int idx = base + lane;
        bool act = idx < g;
        int sn = act ? csr[start + idx] : 0;
        float s = -INFINITY;
        HF vu;
        if (act) {
            HF qu;
            qu.f4 = *(const float4*)(qb + (size_t)sn * HD);
            vu.f4 = *(const float4*)(vb + (size_t)sn * HD);
            float acc_s = 0.f;
            #pragma unroll
            for (int i = 0; i < 4; ++i) {
                float2 t = __half22float2(qu.h2[i]);
                acc_s = fmaf(t.x, kf[2 * i], acc_s);
                acc_s = fmaf(t.y, kf[2 * i + 1], acc_s);
            }
            s = acc_s * 0.35355339059327376f;
        }
        float cm = s;
        #pragma unroll
        for (int off = 1; off < 64; off <<= 1)
            cm = fmaxf(cm, __shfl_xor(cm, off));
        float nm = fmaxf(m, cm);
        float scale = __expf(m - nm);
        m = nm;
        l *= scale;
        #pragma unroll
        for (int i = 0; i < HD; ++i) acc[i] *= scale;
        if (act) {
            float p = __expf(s - nm);
            l += p;
            #pragma unroll
            for (int i = 0; i < 4; ++i) {
                float2 t = __half22float2(vu.h2[i]);
                acc[2 * i] = fmaf(p, t.x, acc[2 * i]);
                acc[2 * i + 1] = fmaf(p, t.y, acc[2 * i + 1]);
            }
        }
    }
    #pragma unroll
    for (int off = 1; off < 64; off <<= 1) {
        l += __shfl_xor(l, off);
        #pragma unroll
        for (int i = 0; i < HD; ++i) acc[i] += __shfl_xor(acc[i], off);
    }
    if (lane == 0) {
        float inv = (l > 0.f) ? 1.0f / l : 0.f;
        float* outp = attn + (size_t)node * D + head * HD;
        float4 o0 = { acc[0] * inv, acc[1] * inv, acc[2] * inv, acc[3] * inv };
        float4 o1 = { acc[4] * inv, acc[5] * inv, acc[6] * inv, acc[7] * inv };
        *(float4*)outp = o0;
        *(float4*)(outp + 4) = o1;
    }
}

// fused: h1 = h + attn@Wo + bo; h = h1 + gelu(h1@W1+b1)@W2 + b2
__global__ __launch_bounds__(256) void k_post(const float* __restrict__ attn,
        const float* __restrict__ Wo, const float* __restrict__ bo,
        const float* __restrict__ W1, const float* __restrict__ b1,
        const float* __restrict__ W2, const float* __restrict__ b2,
        float* __restrict__ h) {
    __shared__ float Wos[D * D], W1s[D * D], W2s[D * D];
    __shared__ float as[8][D], h1s[8][D], ts[8][D];
    for (int i = threadIdx.x; i < D * D; i += 256) {
        Wos[i] = Wo[i]; W1s[i] = W1[i]; W2s[i] = W2[i];
    }
    int ln = threadIdx.x >> 5, col = threadIdx.x & 31;
    int node = blockIdx.x * 8 + ln;
    as[ln][col] = attn[(size_t)node * D + col];
    float hv = h[(size_t)node * D + col];
    __syncthreads();
    float a = bo[col];
    #pragma unroll
    for (int i = 0; i < D; ++i) a = fmaf(as[ln][i], Wos[i * D + col], a);
    float h1 = hv + a;
    h1s[ln][col] = h1;
    __syncthreads();
    float t = b1[col];
    #pragma unroll
    for (int i = 0; i < D; ++i) t = fmaf(h1s[ln][i], W1s[i * D + col], t);
    ts[ln][col] = gelu_f(t);
    __syncthreads();
    float o = b2[col];
    #pragma unroll
    for (int i = 0; i < D; ++i) o = fmaf(ts[ln][i], W2s[i * D + col], o);
    h[(size_t)node * D + col] = h1 + o;
}

// out = h @ W_out + b_out
__global__ void k_out(const float* __restrict__ h, const float* __restrict__ W,
        const float* __restrict__ b, float* __restrict__ out) {
    int n = blockIdx.x * blockDim.x + threadIdx.x;
    if (n >= NN) return;
    const float4* hr = (const float4*)(h + (size_t)n * D);
    float a0 = b[0], a1 = b[1];
    #pragma unroll
    for (int i = 0; i < 8; ++i) {
        float4 hv = hr[i];
        a0 += hv.x * W[(i * 4 + 0) * 2 + 0] + hv.y * W[(i * 4 + 1) * 2 + 0]
            + hv.z * W[(i * 4 + 2) * 2 + 0] + hv.w * W[(i * 4 + 3) * 2 + 0];
        a1 += hv.x * W[(i * 4 + 0) * 2 + 1] + hv.y * W[(i * 4 + 1) * 2 + 1]
            + hv.z * W[(i * 4 + 2) * 2 + 1] + hv.w * W[(i * 4 + 3) * 2 + 1];
    }
    out[n * 2 + 0] = a0;
    out[n * 2 + 1] = a1;
}

extern "C" void kernel_launch(void* const* d_in, const int* in_sizes, int n_in,
                              void* d_out, int out_size, void* d_ws, size_t ws_size,
                              hipStream_t stream) {
    const float* x     = (const float*)d_in[0];
    const int*   src   = (const int*)d_in[1];
    const int*   dst   = (const int*)d_in[2];
    const float* W_in  = (const float*)d_in[3];
    const float* b_in  = (const float*)d_in[4];
    const float* Wq    = (const float*)d_in[5];
    const float* bq    = (const float*)d_in[6];
    const float* Wk    = (const float*)d_in[7];
    const float* bk    = (const float*)d_in[8];
    const float* Wv    = (const float*)d_in[9];
    const float* bv    = (const float*)d_in[10];
    const float* Wo    = (const float*)d_in[11];
    const float* bo    = (const float*)d_in[12];
    const float* W1    = (const float*)d_in[13];
    const float* b1    = (const float*)d_in[14];
    const float* W2    = (const float*)d_in[15];
    const float* b2    = (const float*)d_in[16];
    const float* W_out = (const float*)d_in[17];
    const float* b_out = (const float*)d_in[18];
    float* out = (float*)d_out;

    char* w = (char*)d_ws;
    size_t off = 0;
    auto alloc = [&](size_t bytes) -> void* {
        void* p = w + off;
        off += (bytes + 255) & ~(size_t)255;
        return p;
    };
    float*  h    = (float*)alloc((size_t)NN * D * 4);
    __half* qh   = (__half*)alloc((size_t)NN * D * 2);
    __half* kh   = (__half*)alloc((size_t)NN * D * 2);
    __half* vh   = (__half*)alloc((size_t)NN * D * 2);
    float*  attn = (float*)alloc((size_t)NN * D * 4);  // aliased as tmp during CSR build
    int* deg    = (int*)alloc((size_t)NN * 4);
    int* rs     = (int*)alloc((size_t)NN * 4);
    int* bhist  = (int*)alloc((size_t)NBKT * NBLK * 4);
    int* btot   = (int*)alloc((size_t)NBKT * 4);
    int* bbase  = (int*)alloc((size_t)(NBKT + 1) * 4);
    int* csr    = (int*)alloc((size_t)NE * 4);
    unsigned int* tmp = (unsigned int*)attn;           // NE*4 == NN*D*4 bytes
    (void)ws_size; (void)in_sizes; (void)n_in; (void)out_size;

    k_in_proj<<<NN / 8, 256, 0, stream>>>(x, W_in, b_in, h);
    k_binA<<<NBLK, 256, 0, stream>>>(dst, bhist);
    k_binB1<<<NBKT, NBLK, 0, stream>>>(bhist, btot);
    k_binB2<<<1, 512, 0, stream>>>(btot, bbase);
    k_binC<<<NBLK, 256, 0, stream>>>(src, dst, bhist, bbase, tmp);
    k_binD<<<NBKT, 256, 0, stream>>>(tmp, bbase, csr, rs, deg);

    for (int l = 0; l < 2; ++l) {
        k_qkv<<<NN / 8, 256, 0, stream>>>(h, Wq + l * D * D, bq + l * D,
                                          Wk + l * D * D, bk + l * D,
                                          Wv + l * D * D, bv + l * D, qh, kh, vh);
        k_attn<<<NN, 256, 0, stream>>>(qh, kh, vh, rs, deg, csr, attn);
        k_post<<<NN / 8, 256, 0, stream>>>(attn, Wo + l * D * D, bo + l * D,
                                           W1 + l * D * D, b1 + l * D,
                                           W2 + l * D * D, b2 + l * D, h);
    }
    k_out<<<(NN + 255) / 256, 256, 0, stream>>>(h, W_out, b_out, out);
}

// Round 6
// 427.226 us; speedup vs baseline: 1.7481x; 1.7481x over previous
//
#include <hip/hip_runtime.h>
#include <hip/hip_fp16.h>
#include <math.h>

#define NN 100000
#define NE 3200000
#define INF_ 128
#define D 32
#define H 4
#define HD 8

// binning config: bucket = dst >> 8 (256 dst nodes per bucket)
#define BSH 8
#define BNODES 256
#define NBKT 391                // ceil(100000/256)
#define NBLK 128                // chunking blocks for passes A/C
#define EPB (NE / NBLK)         // 25000 edges per block
#define CAP 12288               // LDS sorted capacity

__device__ __forceinline__ float gelu_f(float x) {
    return 0.5f * x * (1.0f + erff(x * 0.70710678118654752f));
}

// h = gelu(x @ W_in + b_in); block = 256 threads = 8 nodes x 32 cols
__global__ __launch_bounds__(256) void k_in_proj(const float* __restrict__ x,
        const float* __restrict__ W, const float* __restrict__ b,
        float* __restrict__ h) {
    __shared__ float Ws[INF_ * D];     // 16 KB
    __shared__ float xs[8][INF_];      // 4 KB
    for (int i = threadIdx.x; i < INF_ * D; i += 256) Ws[i] = W[i];
    int ln = threadIdx.x >> 5;
    int col = threadIdx.x & 31;
    int node = blockIdx.x * 8 + ln;    // NN/8 = 12500 exact
    const float4* xr = (const float4*)(x + (size_t)node * INF_);
    ((float4*)xs[ln])[col] = xr[col];
    __syncthreads();
    float acc = b[col];
    #pragma unroll 16
    for (int i = 0; i < INF_; ++i) acc = fmaf(xs[ln][i], Ws[i * D + col], acc);
    h[(size_t)node * D + col] = gelu_f(acc);
}

// q,k,v = h @ {Wq,Wk,Wv} + bias; 8 nodes per block; fp16 node-major rows (64B)
__global__ __launch_bounds__(256) void k_qkv(const float* __restrict__ h,
        const float* __restrict__ Wq, const float* __restrict__ bq,
        const float* __restrict__ Wk, const float* __restrict__ bk,
        const float* __restrict__ Wv, const float* __restrict__ bv,
        __half* __restrict__ q, __half* __restrict__ k, __half* __restrict__ v) {
    __shared__ float Ws[3 * D * D];    // 12 KB
    __shared__ float hs[8][D];
    for (int i = threadIdx.x; i < D * D; i += 256) {
        Ws[i] = Wq[i];
        Ws[D * D + i] = Wk[i];
        Ws[2 * D * D + i] = Wv[i];
    }
    int ln = threadIdx.x >> 5, col = threadIdx.x & 31;
    int node = blockIdx.x * 8 + ln;
    hs[ln][col] = h[(size_t)node * D + col];
    __syncthreads();
    float aq = bq[col], ak = bk[col], av = bv[col];
    #pragma unroll
    for (int i = 0; i < D; ++i) {
        float hv = hs[ln][i];
        aq = fmaf(hv, Ws[i * D + col], aq);
        ak = fmaf(hv, Ws[D * D + i * D + col], ak);
        av = fmaf(hv, Ws[2 * D * D + i * D + col], av);
    }
    size_t o = (size_t)node * D + col;
    q[o] = __float2half(aq); k[o] = __float2half(ak); v[o] = __float2half(av);
}

// ---- binned CSR build ----
__global__ __launch_bounds__(256) void k_binA(const int* __restrict__ dst,
        int* __restrict__ bhist) {
    __shared__ int hist[NBKT];
    for (int i = threadIdx.x; i < NBKT; i += 256) hist[i] = 0;
    __syncthreads();
    int base = blockIdx.x * EPB;
    for (int i = threadIdx.x; i < EPB; i += 256)
        atomicAdd(&hist[dst[base + i] >> BSH], 1);
    __syncthreads();
    for (int i = threadIdx.x; i < NBKT; i += 256)
        bhist[i * NBLK + blockIdx.x] = hist[i];
}

__global__ __launch_bounds__(NBLK) void k_binB1(int* __restrict__ bhist,
        int* __restrict__ btot) {
    __shared__ int s[NBLK];
    int b = blockIdx.x;
    int v = bhist[b * NBLK + threadIdx.x];
    s[threadIdx.x] = v;
    __syncthreads();
    for (int off = 1; off < NBLK; off <<= 1) {
        int t = (threadIdx.x >= off) ? s[threadIdx.x - off] : 0;
        __syncthreads();
        s[threadIdx.x] += t;
        __syncthreads();
    }
    bhist[b * NBLK + threadIdx.x] = s[threadIdx.x] - v;
    if (threadIdx.x == NBLK - 1) btot[b] = s[NBLK - 1];
}

__global__ __launch_bounds__(512) void k_binB2(const int* __restrict__ btot,
        int* __restrict__ bbase) {
    __shared__ int s[512];
    int v = (threadIdx.x < NBKT) ? btot[threadIdx.x] : 0;
    s[threadIdx.x] = v;
    __syncthreads();
    for (int off = 1; off < 512; off <<= 1) {
        int t = (threadIdx.x >= off) ? s[threadIdx.x - off] : 0;
        __syncthreads();
        s[threadIdx.x] += t;
        __syncthreads();
    }
    if (threadIdx.x < NBKT) bbase[threadIdx.x] = s[threadIdx.x] - v;
    if (threadIdx.x == NBKT - 1) bbase[NBKT] = s[threadIdx.x];
}

__global__ __launch_bounds__(256) void k_binC(const int* __restrict__ src,
        const int* __restrict__ dst, const int* __restrict__ bhist,
        const int* __restrict__ bbase, unsigned int* __restrict__ tmp) {
    __shared__ int offs[NBKT];
    for (int i = threadIdx.x; i < NBKT; i += 256)
        offs[i] = bhist[i * NBLK + blockIdx.x] + bbase[i];
    __syncthreads();
    int base = blockIdx.x * EPB;
    for (int i = threadIdx.x; i < EPB; i += 256) {
        int d = dst[base + i];
        unsigned int sn = (unsigned int)src[base + i];
        int pos = atomicAdd(&offs[d >> BSH], 1);
        tmp[pos] = sn | ((unsigned int)(d & (BNODES - 1)) << 17);
    }
}

__global__ __launch_bounds__(256) void k_binD(const unsigned int* __restrict__ tmp,
        const int* __restrict__ bbase, int* __restrict__ csr,
        int* __restrict__ rs, int* __restrict__ deg) {
    __shared__ int lcnt[BNODES];
    __shared__ int lscan[BNODES];
    __shared__ int sorted[CAP];
    int b = blockIdx.x;
    int s0 = bbase[b], s1 = bbase[b + 1];
    int len = s1 - s0;
    lcnt[threadIdx.x] = 0;
    __syncthreads();
    for (int i = s0 + threadIdx.x; i < s1; i += 256)
        atomicAdd(&lcnt[tmp[i] >> 17], 1);
    __syncthreads();
    int v = lcnt[threadIdx.x];
    lscan[threadIdx.x] = v;
    __syncthreads();
    for (int off = 1; off < BNODES; off <<= 1) {
        int t = (threadIdx.x >= off) ? lscan[threadIdx.x - off] : 0;
        __syncthreads();
        lscan[threadIdx.x] += t;
        __syncthreads();
    }
    int excl = lscan[threadIdx.x] - v;
    int node = (b << BSH) + threadIdx.x;
    if (node < NN) {
        rs[node] = s0 + excl;
        deg[node] = v;
    }
    lcnt[threadIdx.x] = excl;
    __syncthreads();
    if (len <= CAP) {
        for (int i = s0 + threadIdx.x; i < s1; i += 256) {
            unsigned int p = tmp[i];
            int pos = atomicAdd(&lcnt[p >> 17], 1);
            sorted[pos] = (int)(p & 0x1FFFFu);
        }
        __syncthreads();
        for (int j = threadIdx.x; j < len; j += 256)
            csr[s0 + j] = sorted[j];
    } else {
        for (int i = s0 + threadIdx.x; i < s1; i += 256) {
            unsigned int p = tmp[i];
            int pos = atomicAdd(&lcnt[p >> 17], 1);
            csr[s0 + pos] = (int)(p & 0x1FFFFu);
        }
    }
}

// fused per-dst attention: one wave per node; lanes = 16 edge-slots x 4 heads.
// No max-subtraction (scores are bounded; exp(s)/sum(exp(s)) is exact same math)
// -> no intra-loop cross-lane ops -> 2-deep software-pipelined gathers.
__global__ __launch_bounds__(256) void k_attn(const __half* __restrict__ q,
        const __half* __restrict__ kk, const __half* __restrict__ vv,
        const int* __restrict__ rs, const int* __restrict__ deg,
        const int* __restrict__ csr, float* __restrict__ attn) {
    int wid = (blockIdx.x * 256 + threadIdx.x) >> 6;
    int lane = threadIdx.x & 63;
    if (wid >= NN) return;
    int eslot = lane >> 2, head = lane & 3;
    int start = rs[wid], g = deg[wid];
    union HF { float4 f4; __half2 h2[4]; };
    HF ku;
    ku.f4 = *(const float4*)(kk + (size_t)wid * D + head * HD);
    float kf[HD];
    #pragma unroll
    for (int i = 0; i < 4; ++i) {
        float2 t = __half22float2(ku.h2[i]);
        kf[2 * i] = t.x; kf[2 * i + 1] = t.y;
    }
    float l = 0.f;
    float acc[HD];
    #pragma unroll
    for (int i = 0; i < HD; ++i) acc[i] = 0.f;

    int C = (g + 15) >> 4;                 // chunks of 16 edges
    bool act = eslot < g;
    HF qu, vu;
    if (act) {
        int sn = csr[start + eslot];
        qu.f4 = *(const float4*)(q + (size_t)sn * D + head * HD);
        vu.f4 = *(const float4*)(vv + (size_t)sn * D + head * HD);
    }
    for (int c = 1; c < C; ++c) {
        int idx2 = c * 16 + eslot;
        bool act2 = idx2 < g;
        HF qu2, vu2;
        if (act2) {
            int sn2 = csr[start + idx2];
            qu2.f4 = *(const float4*)(q + (size_t)sn2 * D + head * HD);
            vu2.f4 = *(const float4*)(vv + (size_t)sn2 * D + head * HD);
        }
        if (act) {
            float s = 0.f;
            #pragma unroll
            for (int i = 0; i < 4; ++i) {
                float2 t = __half22float2(qu.h2[i]);
                s = fmaf(t.x, kf[2 * i], s);
                s = fmaf(t.y, kf[2 * i + 1], s);
            }
            float p = __expf(s * 0.35355339059327376f);
            l += p;
            #pragma unroll
            for (int i = 0; i < 4; ++i) {
                float2 t = __half22float2(vu.h2[i]);
                acc[2 * i] = fmaf(p, t.x, acc[2 * i]);
                acc[2 * i + 1] = fmaf(p, t.y, acc[2 * i + 1]);
            }
        }
        act = act2; qu = qu2; vu = vu2;
    }
    if (act) {
        float s = 0.f;
        #pragma unroll
        for (int i = 0; i < 4; ++i) {
            float2 t = __half22float2(qu.h2[i]);
            s = fmaf(t.x, kf[2 * i], s);
            s = fmaf(t.y, kf[2 * i + 1], s);
        }
        float p = __expf(s * 0.35355339059327376f);
        l += p;
        #pragma unroll
        for (int i = 0; i < 4; ++i) {
            float2 t = __half22float2(vu.h2[i]);
            acc[2 * i] = fmaf(p, t.x, acc[2 * i]);
            acc[2 * i + 1] = fmaf(p, t.y, acc[2 * i + 1]);
        }
    }
    // final reduce across the 16 edge-slot lanes (stride 4)
    #pragma unroll
    for (int off = 4; off < 64; off <<= 1) {
        l += __shfl_xor(l, off);
        #pragma unroll
        for (int i = 0; i < HD; ++i) acc[i] += __shfl_xor(acc[i], off);
    }
    if (eslot == 0) {
        float inv = (l > 0.f) ? 1.0f / l : 0.f;
        float* outp = attn + (size_t)wid * D + head * HD;
        float4 o0 = { acc[0] * inv, acc[1] * inv, acc[2] * inv, acc[3] * inv };
        float4 o1 = { acc[4] * inv, acc[5] * inv, acc[6] * inv, acc[7] * inv };
        *(float4*)outp = o0;
        *(float4*)(outp + 4) = o1;
    }
}

// fused: h1 = h + attn@Wo + bo; h = h1 + gelu(h1@W1+b1)@W2 + b2
__global__ __launch_bounds__(256) void k_post(const float* __restrict__ attn,
        const float* __restrict__ Wo, const float* __restrict__ bo,
        const float* __restrict__ W1, const float* __restrict__ b1,
        const float* __restrict__ W2, const float* __restrict__ b2,
        float* __restrict__ h) {
    __shared__ float Wos[D * D], W1s[D * D], W2s[D * D];
    __shared__ float as[8][D], h1s[8][D], ts[8][D];
    for (int i = threadIdx.x; i < D * D; i += 256) {
        Wos[i] = Wo[i]; W1s[i] = W1[i]; W2s[i] = W2[i];
    }
    int ln = threadIdx.x >> 5, col = threadIdx.x & 31;
    int node = blockIdx.x * 8 + ln;
    as[ln][col] = attn[(size_t)node * D + col];
    float hv = h[(size_t)node * D + col];
    __syncthreads();
    float a = bo[col];
    #pragma unroll
    for (int i = 0; i < D; ++i) a = fmaf(as[ln][i], Wos[i * D + col], a);
    float h1 = hv + a;
    h1s[ln][col] = h1;
    __syncthreads();
    float t = b1[col];
    #pragma unroll
    for (int i = 0; i < D; ++i) t = fmaf(h1s[ln][i], W1s[i * D + col], t);
    ts[ln][col] = gelu_f(t);
    __syncthreads();
    float o = b2[col];
    #pragma unroll
    for (int i = 0; i < D; ++i) o = fmaf(ts[ln][i], W2s[i * D + col], o);
    h[(size_t)node * D + col] = h1 + o;
}

// out = h @ W_out + b_out
__global__ void k_out(const float* __restrict__ h, const float* __restrict__ W,
        const float* __restrict__ b, float* __restrict__ out) {
    int n = blockIdx.x * blockDim.x + threadIdx.x;
    if (n >= NN) return;
    const float4* hr = (const float4*)(h + (size_t)n * D);
    float a0 = b[0], a1 = b[1];
    #pragma unroll
    for (int i = 0; i < 8; ++i) {
        float4 hv = hr[i];
        a0 += hv.x * W[(i * 4 + 0) * 2 + 0] + hv.y * W[(i * 4 + 1) * 2 + 0]
            + hv.z * W[(i * 4 + 2) * 2 + 0] + hv.w * W[(i * 4 + 3) * 2 + 0];
        a1 += hv.x * W[(i * 4 + 0) * 2 + 1] + hv.y * W[(i * 4 + 1) * 2 + 1]
            + hv.z * W[(i * 4 + 2) * 2 + 1] + hv.w * W[(i * 4 + 3) * 2 + 1];
    }
    out[n * 2 + 0] = a0;
    out[n * 2 + 1] = a1;
}

extern "C" void kernel_launch(void* const* d_in, const int* in_sizes, int n_in,
                              void* d_out, int out_size, void* d_ws, size_t ws_size,
                              hipStream_t stream) {
    const float* x     = (const float*)d_in[0];
    const int*   src   = (const int*)d_in[1];
    const int*   dst   = (const int*)d_in[2];
    const float* W_in  = (const float*)d_in[3];
    const float* b_in  = (const float*)d_in[4];
    const float* Wq    = (const float*)d_in[5];
    const float* bq    = (const float*)d_in[6];
    const float* Wk    = (const float*)d_in[7];
    const float* bk    = (const float*)d_in[8];
    const float* Wv    = (const float*)d_in[9];
    const float* bv    = (const float*)d_in[10];
    const float* Wo    = (const float*)d_in[11];
    const float* bo    = (const float*)d_in[12];
    const float* W1    = (const float*)d_in[13];
    const float* b1    = (const float*)d_in[14];
    const float* W2    = (const float*)d_in[15];
    const float* b2    = (const float*)d_in[16];
    const float* W_out = (const float*)d_in[17];
    const float* b_out = (const float*)d_in[18];
    float* out = (float*)d_out;

    char* w = (char*)d_ws;
    size_t off = 0;
    auto alloc = [&](size_t bytes) -> void* {
        void* p = w + off;
        off += (bytes + 255) & ~(size_t)255;
        return p;
    };
    float*  h    = (float*)alloc((size_t)NN * D * 4);
    __half* q    = (__half*)alloc((size_t)NN * D * 2);
    __half* kk   = (__half*)alloc((size_t)NN * D * 2);
    __half* vv   = (__half*)alloc((size_t)NN * D * 2);
    float*  attn = (float*)alloc((size_t)NN * D * 4);  // aliased as tmp during CSR build
    int* deg    = (int*)alloc((size_t)NN * 4);
    int* rs     = (int*)alloc((size_t)NN * 4);
    int* bhist  = (int*)alloc((size_t)NBKT * NBLK * 4);
    int* btot   = (int*)alloc((size_t)NBKT * 4);
    int* bbase  = (int*)alloc((size_t)(NBKT + 1) * 4);
    int* csr    = (int*)alloc((size_t)NE * 4);
    unsigned int* tmp = (unsigned int*)attn;           // NE*4 == NN*D*4 bytes
    (void)ws_size; (void)in_sizes; (void)n_in; (void)out_size;

    k_in_proj<<<NN / 8, 256, 0, stream>>>(x, W_in, b_in, h);
    k_binA<<<NBLK, 256, 0, stream>>>(dst, bhist);
    k_binB1<<<NBKT, NBLK, 0, stream>>>(bhist, btot);
    k_binB2<<<1, 512, 0, stream>>>(btot, bbase);
    k_binC<<<NBLK, 256, 0, stream>>>(src, dst, bhist, bbase, tmp);
    k_binD<<<NBKT, 256, 0, stream>>>(tmp, bbase, csr, rs, deg);

    for (int l = 0; l < 2; ++l) {
        k_qkv<<<NN / 8, 256, 0, stream>>>(h, Wq + l * D * D, bq + l * D,
                                          Wk + l * D * D, bk + l * D,
                                          Wv + l * D * D, bv + l * D, q, kk, vv);
        k_attn<<<NN / 4, 256, 0, stream>>>(q, kk, vv, rs, deg, csr, attn);
        k_post<<<NN / 8, 256, 0, stream>>>(attn, Wo + l * D * D, bo + l * D,
                                           W1 + l * D * D, b1 + l * D,
                                           W2 + l * D * D, b2 + l * D, h);
    }
    k_out<<<(NN + 255) / 256, 256, 0, stream>>>(h, W_out, b_out, out);
}